// Round 7
// baseline (372.898 us; speedup 1.0000x reference)
//
#include <hip/hip_runtime.h>

// Problem geometry (from reference setup_inputs): B=128, S=256, H=768, K=64.
#define SEQ 256
#define HID 768
#define KLEN 64
#define H4 (HID / 4)          // 192 float4 per row
#define ROWS_PER_WAVE 4       // consecutive rows per wave (4 divides SEQ -> same batch)
#define BLOCK 256
#define WAVES_PER_BLOCK (BLOCK / 64)

// Native vector type so __builtin_nontemporal_* accepts it (HIP's float4 is a struct).
typedef float f4 __attribute__((ext_vector_type(4)));

// One wave owns ROWS_PER_WAVE consecutive (b,s) rows (same batch b).
// Lists loaded once per wave; per row: 5 wave-uniform __any ballots; data moved
// as nontemporal float4 (write-once outputs should not pollute L2).
__global__ __launch_bounds__(BLOCK) void dlcf_dca_fused(
    const f4* __restrict__ x4,            // [B*S*H/4]
    const int* __restrict__ depend,       // [B, K]
    const int* __restrict__ depended,     // [B, K]
    const int* __restrict__ no_connect,   // [B, K]
    const float* __restrict__ dep_w,      // [B]
    const float* __restrict__ dpd_w,      // [B]
    f4* __restrict__ o4,                  // 3 x [B*S*H/4] concatenated
    size_t n4)                            // float4 count per output tensor
{
    const int lane  = threadIdx.x & 63;
    const int wid   = threadIdx.x >> 6;
    const int chunk = blockIdx.x * WAVES_PER_BLOCK + wid;
    const int row0  = chunk * ROWS_PER_WAVE;     // first row of this wave's chunk
    const int b     = row0 >> 8;                 // row0 / SEQ (constant over chunk)

    // Lane k holds entry k of each list for this batch (loaded once per wave).
    const int e_dep = depend[b * KLEN + lane];
    const int e_dpd = depended[b * KLEN + lane];
    const int e_noc = no_connect[b * KLEN + lane];
    const bool dep_ok = (e_dep != -1) & (e_dep + 1 < SEQ);  // validity for output 2
    const bool dpd_ok = (e_dpd != -1) & (e_dpd + 1 < SEQ);
    const bool noc_ok = (e_noc != -1) & (e_noc + 1 < SEQ);
    const float w1 = dep_w[b];
    const float w2 = dpd_w[b];

    #pragma unroll
    for (int i = 0; i < ROWS_PER_WAVE; ++i) {
        const int r = row0 + i;
        const int s = r & (SEQ - 1);
        const int t = s - 1;

        // Raw membership (outputs 0/1): no validity check, exactly as reference.
        const bool dep_raw = __any(e_dep == t);
        const bool dpd_raw = __any(e_dpd == t);
        // Valid membership (output 2).
        const bool dep_mem = __any((e_dep == t) & dep_ok);
        const bool dpd_mem = __any((e_dpd == t) & dpd_ok);
        const bool noc_mem = __any((e_noc == t) & noc_ok);

        const float m0 = (s == 0 || dep_raw) ? 1.0f : 0.0f;
        const float m1 = (s == 0 || dpd_raw) ? 1.0f : 0.0f;
        // Priority chain (reference `where` order, last write wins):
        // pos==0 -> 1; no_connect -> 0; depended -> w2; depend -> w1; else 0.
        float m2;
        if (s == 0)        m2 = 1.0f;
        else if (noc_mem)  m2 = 0.0f;
        else if (dpd_mem)  m2 = w2;
        else if (dep_mem)  m2 = w1;
        else               m2 = 0.0f;

        const size_t base = (size_t)r * H4 + lane;
        #pragma unroll
        for (int j = 0; j < H4 / 64; ++j) {      // 3 float4 per lane per row
            const size_t idx = base + (size_t)j * 64;
            const f4 v = __builtin_nontemporal_load(&x4[idx]);
            __builtin_nontemporal_store(v * m0, &o4[idx]);
            __builtin_nontemporal_store(v * m1, &o4[idx + n4]);
            __builtin_nontemporal_store(v * m2, &o4[idx + 2 * n4]);
        }
    }
}

extern "C" void kernel_launch(void* const* d_in, const int* in_sizes, int n_in,
                              void* d_out, int out_size, void* d_ws, size_t ws_size,
                              hipStream_t stream) {
    const f4*    x4         = (const f4*)d_in[0];
    const int*   depend     = (const int*)d_in[1];
    const int*   depended   = (const int*)d_in[2];
    const int*   no_connect = (const int*)d_in[3];
    const float* dep_w      = (const float*)d_in[4];
    const float* dpd_w      = (const float*)d_in[5];
    f4* o4 = (f4*)d_out;

    const int B = in_sizes[0] / (SEQ * HID);          // 128
    const size_t n4 = (size_t)in_sizes[0] / 4;        // float4 per output tensor
    const int rows = B * SEQ;                         // 32768
    const int grid = rows / (ROWS_PER_WAVE * WAVES_PER_BLOCK);  // 2048

    dlcf_dca_fused<<<grid, BLOCK, 0, stream>>>(
        x4, depend, depended, no_connect, dep_w, dpd_w, o4, n4);
}

// Round 9
// 364.290 us; speedup vs baseline: 1.0236x; 1.0236x over previous
//
#include <hip/hip_runtime.h>

// Problem geometry (from reference setup_inputs): B=128, S=256, H=768, K=64.
#define SEQ 256
#define HID 768
#define KLEN 64
#define H4 (HID / 4)   // 192 float4 per row

// One block per (b, s) row. 192 threads = 3 waves of 64 (R4 baseline structure).
// Each wave computes membership with lane k holding list[b][k], reduced via
// __any (wave-uniform). NEW: rows where all three multipliers are zero skip
// the x-load entirely and just store zeros (~60% of rows; read 96 -> ~40 MB).
__global__ __launch_bounds__(192) void dlcf_dca_fused(
    const float* __restrict__ x,          // [B, S, H]
    const int*   __restrict__ depend,     // [B, K]
    const int*   __restrict__ depended,   // [B, K]
    const int*   __restrict__ no_connect, // [B, K]
    const float* __restrict__ dep_w,      // [B]
    const float* __restrict__ dpd_w,      // [B]
    float* __restrict__ out,              // 3 x [B, S, H] concatenated
    size_t n4)                            // B*S*H/4 (float4 count per output)
{
    const int r    = blockIdx.x;      // row index in [0, B*S)
    const int b    = r >> 8;          // r / SEQ
    const int s    = r & (SEQ - 1);   // r % SEQ
    const int lane = threadIdx.x & 63;
    const int target = s - 1;

    // Lane k holds entry k of each list for this batch.
    const int e_dep = depend[b * KLEN + lane];
    const int e_dpd = depended[b * KLEN + lane];
    const int e_noc = no_connect[b * KLEN + lane];

    // Raw membership (outputs 0/1): no validity check, exactly as reference.
    const bool dep_raw = __any(e_dep == target);
    const bool dpd_raw = __any(e_dpd == target);

    // Valid membership (output 2): idx != -1 and idx+1 < S.
    const bool dep_mem = __any((e_dep == target) & (e_dep != -1) & (e_dep + 1 < SEQ));
    const bool dpd_mem = __any((e_dpd == target) & (e_dpd != -1) & (e_dpd + 1 < SEQ));
    const bool noc_mem = __any((e_noc == target) & (e_noc != -1) & (e_noc + 1 < SEQ));

    const float m0 = (s == 0 || dep_raw) ? 1.0f : 0.0f;
    const float m1 = (s == 0 || dpd_raw) ? 1.0f : 0.0f;

    // Priority chain (reference `where` order, last write wins):
    // pos==0 -> 1; no_connect -> 0; depended -> dpd_w; depend -> dep_w; else 0.
    float m2;
    if (s == 0)        m2 = 1.0f;
    else if (noc_mem)  m2 = 0.0f;
    else if (dpd_mem)  m2 = dpd_w[b];
    else if (dep_mem)  m2 = dep_w[b];
    else               m2 = 0.0f;

    const size_t base = (size_t)r * H4 + threadIdx.x;
    const float4* __restrict__ x4 = (const float4*)x;
    float4* __restrict__ o4 = (float4*)out;

    // Wave-uniform (in fact block-uniform) condition: no divergence.
    if (m0 == 0.0f && m1 == 0.0f && m2 == 0.0f) {
        const float4 z = make_float4(0.f, 0.f, 0.f, 0.f);
        o4[base]          = z;
        o4[base + n4]     = z;
        o4[base + 2 * n4] = z;
        return;
    }

    const float4 v = x4[base];
    o4[base]          = make_float4(v.x * m0, v.y * m0, v.z * m0, v.w * m0);
    o4[base + n4]     = make_float4(v.x * m1, v.y * m1, v.z * m1, v.w * m1);
    o4[base + 2 * n4] = make_float4(v.x * m2, v.y * m2, v.z * m2, v.w * m2);
}

extern "C" void kernel_launch(void* const* d_in, const int* in_sizes, int n_in,
                              void* d_out, int out_size, void* d_ws, size_t ws_size,
                              hipStream_t stream) {
    const float* x          = (const float*)d_in[0];
    const int*   depend     = (const int*)d_in[1];
    const int*   depended   = (const int*)d_in[2];
    const int*   no_connect = (const int*)d_in[3];
    const float* dep_w      = (const float*)d_in[4];
    const float* dpd_w      = (const float*)d_in[5];
    float* out = (float*)d_out;

    const int B = in_sizes[0] / (SEQ * HID);      // 128
    const size_t n4 = (size_t)in_sizes[0] / 4;    // float4 per output tensor

    dlcf_dca_fused<<<B * SEQ, 192, 0, stream>>>(
        x, depend, depended, no_connect, dep_w, dpd_w, out, n4);
}